// Round 9
// baseline (400.862 us; speedup 1.0000x reference)
//
#include <hip/hip_runtime.h>
#include <hip/hip_bf16.h>
#include <stdint.h>

#define IN_CH 128
#define NPB   448            // nodes per bucket
#define NBUCK 224            // NBUCK*NPB = 100352 >= N
#define CAP   8192           // edge capacity per bucket region (avg ~7150)
#define PART_EPB 2048        // edges per partition block
#define SRC_BITS 17          // src < 131072
#define SRC_MASK ((1 << SRC_BITS) - 1)

typedef short v8s __attribute__((ext_vector_type(8)));
typedef float v4f __attribute__((ext_vector_type(4)));

__device__ __forceinline__ ushort f2b(float f) {
    return ((__hip_bfloat16_raw)__float2bfloat16(f)).x;
}
__device__ __forceinline__ float b2f(ushort u) {
    __hip_bfloat16_raw r; r.x = u;
    return __bfloat162float((__hip_bfloat16)r);
}

// ---------------------------------- coalesced radix partition of edges by dst
__global__ __launch_bounds__(256) void k_part(
    const int* __restrict__ src, const int* __restrict__ dst,
    int* __restrict__ cursor, int* __restrict__ ebuf, int E) {
    __shared__ int sedge[PART_EPB];                    // 8 KB
    __shared__ int h[NBUCK], lofs[NBUCK], gbase[NBUCK], lcur[NBUCK];
    __shared__ int ssc[256];

    int tid = threadIdx.x;
    int eb0 = blockIdx.x * PART_EPB;
    int cnt = min(PART_EPB, E - eb0);

    if (tid < NBUCK) { h[tid] = 0; lcur[tid] = 0; }
    __syncthreads();
    for (int i = tid; i < cnt; i += 256)
        atomicAdd(&h[dst[eb0 + i] / NPB], 1);
    __syncthreads();
    int v = (tid < NBUCK) ? h[tid] : 0;
    ssc[tid] = v;
    __syncthreads();
    for (int off = 1; off < 256; off <<= 1) {
        int val = (tid >= off) ? ssc[tid - off] : 0;
        __syncthreads();
        ssc[tid] += val;
        __syncthreads();
    }
    int excl = ssc[tid] - v;
    if (tid < NBUCK) {
        lofs[tid] = excl;
        gbase[tid] = tid * CAP + atomicAdd(&cursor[tid], v);
    }
    __syncthreads();
    for (int i = tid; i < cnt; i += 256) {
        int s0 = src[eb0 + i];
        int d0 = dst[eb0 + i];
        int b = d0 / NPB;
        int dl = d0 - b * NPB;
        int p = atomicAdd(&lcur[b], 1);
        sedge[lofs[b] + p] = (dl << SRC_BITS) | s0;
    }
    __syncthreads();
    for (int i = tid; i < cnt; i += 256) {
        int lo = 0, hi = NBUCK - 1;
        while (lo < hi) {
            int mid = (lo + hi + 1) >> 1;
            if (lofs[mid] <= i) lo = mid; else hi = mid - 1;
        }
        int pos = gbase[lo] + (i - lofs[lo]);
        if (pos < (lo + 1) * CAP) ebuf[pos] = sedge[i];  // overflow guard
    }
}

// ---------------------- per-bucket CSR build: hist -> scan -> scatter, L2-local
__global__ __launch_bounds__(512) void k_bbuild(
    const int* __restrict__ ebuf, const int* __restrict__ cursor,
    int* __restrict__ row_ptr, int* __restrict__ deg,
    int* __restrict__ col, int N) {
    __shared__ int sdeg[NPB];
    __shared__ int scur[NPB];
    __shared__ int ssum[512];
    int b = blockIdx.x, tid = threadIdx.x;
    int base = b * NPB;
    int nodes = min(NPB, N - base);
    int e0 = b * CAP;
    int e1 = e0 + min(cursor[b], CAP);

    if (tid < NPB) sdeg[tid] = 0;
    __syncthreads();
    for (int e = e0 + tid; e < e1; e += 512)
        atomicAdd(&sdeg[((unsigned)ebuf[e]) >> SRC_BITS], 1);
    __syncthreads();
    int v = (tid < NPB) ? sdeg[tid] : 0;
    ssum[tid] = v;
    __syncthreads();
    for (int off = 1; off < 512; off <<= 1) {
        int val = (tid >= off) ? ssum[tid - off] : 0;
        __syncthreads();
        ssum[tid] += val;
        __syncthreads();
    }
    int excl = ssum[tid] - v;
    if (tid < NPB) {
        scur[tid] = excl;
        if (tid < nodes) {
            row_ptr[base + tid] = e0 + excl;
            deg[base + tid] = v;
        }
    }
    __syncthreads();
    for (int e = e0 + tid; e < e1; e += 512) {
        int w = ebuf[e];
        int dl = ((unsigned)w) >> SRC_BITS;
        int p = atomicAdd(&scur[dl], 1);
        col[e0 + p] = w & SRC_MASK;
    }
}

// ------------------------------------------------- MFMA GEMM, W in LDS
// Operand-swapped: a = W-frag (rows = out channels), b = node-frag.
// D: row(quad*4+reg) = channel, col(m16) = node -> per-lane ushort4/float4 stores.
// MODE 0 (layer 1): A = x fp32 (in-register cast), OC=256.
//   c<64 -> q1 plane0 [N][64], 64<=c<128 -> q1 plane1 [N][64] (time-split gather
//   targets), c>=128 -> p1 [N][128] bf16.
// MODE 1 (layer 2): A = hb bf16, OC=128. c<64 -> q2[N][64] bf16, c>=64 -> p2[N][64] f32.
template <int OC, int MODE>
__global__ __launch_bounds__(256) void k_wgemm(
    const float* __restrict__ Af, const ushort* __restrict__ Ab,
    const float* __restrict__ WlF, const float* __restrict__ WrF,
    ushort* __restrict__ q1, ushort* __restrict__ p1,
    ushort* __restrict__ q2, float* __restrict__ p2, int N) {
    const int NT = OC / 16;
    const int LDW = 128 + 8;
    __shared__ ushort Wlds[OC * LDW];

    int tid = threadIdx.x;
    // stage + cast W from fp32: OC rows x 128 k
    for (int it = 0; it < OC / 16; it++) {
        int idx = it * 256 + tid;
        int r = idx >> 4, kc = (idx & 15) * 8;
        const float* Wrow = (r < OC / 2) ? (WlF + (size_t)r * 128)
                                         : (WrF + (size_t)(r - OC / 2) * 128);
        float4 w0 = *(const float4*)(Wrow + kc);
        float4 w1 = *(const float4*)(Wrow + kc + 4);
        v8s wv;
        wv[0] = (short)f2b(w0.x); wv[1] = (short)f2b(w0.y);
        wv[2] = (short)f2b(w0.z); wv[3] = (short)f2b(w0.w);
        wv[4] = (short)f2b(w1.x); wv[5] = (short)f2b(w1.y);
        wv[6] = (short)f2b(w1.z); wv[7] = (short)f2b(w1.w);
        *(v8s*)((short*)Wlds + r * LDW + kc) = wv;
    }
    __syncthreads();

    int wave = tid >> 6;
    int lane = tid & 63;
    int m16 = lane & 15;
    int quad = lane >> 4;
    int rowbase = blockIdx.x * 128 + wave * 32;

    v4f acc[2][NT];
#pragma unroll
    for (int mt = 0; mt < 2; mt++)
#pragma unroll
        for (int t = 0; t < NT; t++) acc[mt][t] = {0.f, 0.f, 0.f, 0.f};

    int ar0 = min(rowbase + m16, N - 1);
    int ar1 = min(rowbase + 16 + m16, N - 1);

#pragma unroll
    for (int ks = 0; ks < 4; ks++) {
        int k0 = ks * 32 + quad * 8;
        v8s b0, b1;   // node-row fragments (B operand)
        if (MODE == 0) {
            float4 f00 = *(const float4*)(Af + (size_t)ar0 * 128 + k0);
            float4 f01 = *(const float4*)(Af + (size_t)ar0 * 128 + k0 + 4);
            float4 f10 = *(const float4*)(Af + (size_t)ar1 * 128 + k0);
            float4 f11 = *(const float4*)(Af + (size_t)ar1 * 128 + k0 + 4);
            b0[0] = (short)f2b(f00.x); b0[1] = (short)f2b(f00.y);
            b0[2] = (short)f2b(f00.z); b0[3] = (short)f2b(f00.w);
            b0[4] = (short)f2b(f01.x); b0[5] = (short)f2b(f01.y);
            b0[6] = (short)f2b(f01.z); b0[7] = (short)f2b(f01.w);
            b1[0] = (short)f2b(f10.x); b1[1] = (short)f2b(f10.y);
            b1[2] = (short)f2b(f10.z); b1[3] = (short)f2b(f10.w);
            b1[4] = (short)f2b(f11.x); b1[5] = (short)f2b(f11.y);
            b1[6] = (short)f2b(f11.z); b1[7] = (short)f2b(f11.w);
        } else {
            b0 = *(const v8s*)((const short*)Ab + (size_t)ar0 * 128 + k0);
            b1 = *(const v8s*)((const short*)Ab + (size_t)ar1 * 128 + k0);
        }
#pragma unroll
        for (int t = 0; t < NT; t++) {
            v8s aW = *(const v8s*)((const short*)Wlds + (t * 16 + m16) * LDW + k0);
            acc[0][t] = __builtin_amdgcn_mfma_f32_16x16x32_bf16(aW, b0, acc[0][t], 0, 0, 0);
            acc[1][t] = __builtin_amdgcn_mfma_f32_16x16x32_bf16(aW, b1, acc[1][t], 0, 0, 0);
        }
    }

    // D: channel = t*16 + quad*4 + r, node = rowbase + mt*16 + m16
#pragma unroll
    for (int mt = 0; mt < 2; mt++) {
        int node = rowbase + mt * 16 + m16;
        if (node < N) {
#pragma unroll
            for (int t = 0; t < NT; t++) {
                int c0 = t * 16 + quad * 4;
                float v0 = acc[mt][t][0], v1 = acc[mt][t][1];
                float v2 = acc[mt][t][2], v3 = acc[mt][t][3];
                if (MODE == 0) {
                    if (c0 < 128) {
                        ushort4 o;
                        o.x = f2b(v0); o.y = f2b(v1); o.z = f2b(v2); o.w = f2b(v3);
                        int plane = c0 >> 6;
                        *(ushort4*)(q1 + (size_t)plane * N * 64 +
                                    (size_t)node * 64 + (c0 & 63)) = o;
                    } else {
                        ushort4 o;
                        o.x = f2b(v0); o.y = f2b(v1); o.z = f2b(v2); o.w = f2b(v3);
                        *(ushort4*)(p1 + (size_t)node * 128 + (c0 - 128)) = o;
                    }
                } else {
                    if (c0 < 64) {
                        ushort4 o;
                        o.x = f2b(v0); o.y = f2b(v1); o.z = f2b(v2); o.w = f2b(v3);
                        *(ushort4*)(q2 + (size_t)node * 64 + c0) = o;
                    } else {
                        float4 o = {v0, v1, v2, v3};
                        *(float4*)(p2 + (size_t)node * 64 + (c0 - 64)) = o;
                    }
                }
            }
        }
    }
}

// ------------------- layer-1 aggregation, one 64-ch plane per launch:
// h[ch] = ReLU(mean(Q1plane)[ch] + P1[ch] + b1[ch]) -> bf16
// 1 wave/node; 32-lane half-waves each gather one edge's 128B plane row;
// 8 slots -> 16 rows in flight/wave; shfl_xor(32) combine.
__global__ void k_agg1(const int* __restrict__ row_ptr, const int* __restrict__ deg,
                       const int* __restrict__ col, const ushort* __restrict__ qpl,
                       const ushort* __restrict__ p1, const float* __restrict__ bias,
                       ushort* __restrict__ hb, int N, int chbase) {
    int node = blockIdx.x * (blockDim.x >> 6) + (threadIdx.x >> 6);
    int lane = threadIdx.x & 63;
    if (node >= N) return;
    int s0 = row_ptr[node];
    int dn = deg[node];
    int s1 = s0 + dn;
    int half = lane >> 5, cl = lane & 31;
    int ch = 2 * cl;
    float ax = 0.f, ay = 0.f;
    int j = s0;
    for (; j + 16 <= s1; j += 16) {
        int c0 = col[j + half],      c1 = col[j + 2 + half];
        int c2 = col[j + 4 + half],  c3 = col[j + 6 + half];
        int c4 = col[j + 8 + half],  c5 = col[j + 10 + half];
        int c6 = col[j + 12 + half], c7 = col[j + 14 + half];
        ushort2 v0 = *(const ushort2*)(qpl + (size_t)c0 * 64 + ch);
        ushort2 v1 = *(const ushort2*)(qpl + (size_t)c1 * 64 + ch);
        ushort2 v2 = *(const ushort2*)(qpl + (size_t)c2 * 64 + ch);
        ushort2 v3 = *(const ushort2*)(qpl + (size_t)c3 * 64 + ch);
        ushort2 v4 = *(const ushort2*)(qpl + (size_t)c4 * 64 + ch);
        ushort2 v5 = *(const ushort2*)(qpl + (size_t)c5 * 64 + ch);
        ushort2 v6 = *(const ushort2*)(qpl + (size_t)c6 * 64 + ch);
        ushort2 v7 = *(const ushort2*)(qpl + (size_t)c7 * 64 + ch);
        ax += b2f(v0.x) + b2f(v1.x) + b2f(v2.x) + b2f(v3.x)
            + b2f(v4.x) + b2f(v5.x) + b2f(v6.x) + b2f(v7.x);
        ay += b2f(v0.y) + b2f(v1.y) + b2f(v2.y) + b2f(v3.y)
            + b2f(v4.y) + b2f(v5.y) + b2f(v6.y) + b2f(v7.y);
    }
    for (; j + half < s1; j += 2) {
        ushort2 v = *(const ushort2*)(qpl + (size_t)col[j + half] * 64 + ch);
        ax += b2f(v.x); ay += b2f(v.y);
    }
    ax += __shfl_xor(ax, 32);
    ay += __shfl_xor(ay, 32);
    if (half == 0) {
        float inv = (dn > 0) ? 1.0f / (float)dn : 0.0f;
        ushort2 pb = *(const ushort2*)(p1 + (size_t)node * 128 + chbase + ch);
        float2 bi = *(const float2*)(bias + chbase + ch);
        ushort2 o;
        o.x = f2b(fmaxf(ax * inv + b2f(pb.x) + bi.x, 0.f));
        o.y = f2b(fmaxf(ay * inv + b2f(pb.y) + bi.y, 0.f));
        *(ushort2*)(hb + (size_t)node * 128 + chbase + ch) = o;
    }
}

// ------------------- layer-2 aggregation: out = mean(Q2) + P2 + b2 -> fp32
__global__ void k_agg2(const int* __restrict__ row_ptr, const int* __restrict__ deg,
                       const int* __restrict__ col, const ushort* __restrict__ q2,
                       const float* __restrict__ p2, const float* __restrict__ bias,
                       float* __restrict__ out, int N) {
    int node = blockIdx.x * (blockDim.x >> 6) + (threadIdx.x >> 6);
    int lane = threadIdx.x & 63;
    if (node >= N) return;
    int s0 = row_ptr[node];
    int dn = deg[node];
    int s1 = s0 + dn;
    int half = lane >> 5, cl = lane & 31;
    int ch = 2 * cl;
    float ax = 0.f, ay = 0.f;
    int j = s0;
    for (; j + 16 <= s1; j += 16) {
        int c0 = col[j + half],      c1 = col[j + 2 + half];
        int c2 = col[j + 4 + half],  c3 = col[j + 6 + half];
        int c4 = col[j + 8 + half],  c5 = col[j + 10 + half];
        int c6 = col[j + 12 + half], c7 = col[j + 14 + half];
        ushort2 v0 = *(const ushort2*)(q2 + (size_t)c0 * 64 + ch);
        ushort2 v1 = *(const ushort2*)(q2 + (size_t)c1 * 64 + ch);
        ushort2 v2 = *(const ushort2*)(q2 + (size_t)c2 * 64 + ch);
        ushort2 v3 = *(const ushort2*)(q2 + (size_t)c3 * 64 + ch);
        ushort2 v4 = *(const ushort2*)(q2 + (size_t)c4 * 64 + ch);
        ushort2 v5 = *(const ushort2*)(q2 + (size_t)c5 * 64 + ch);
        ushort2 v6 = *(const ushort2*)(q2 + (size_t)c6 * 64 + ch);
        ushort2 v7 = *(const ushort2*)(q2 + (size_t)c7 * 64 + ch);
        ax += b2f(v0.x) + b2f(v1.x) + b2f(v2.x) + b2f(v3.x)
            + b2f(v4.x) + b2f(v5.x) + b2f(v6.x) + b2f(v7.x);
        ay += b2f(v0.y) + b2f(v1.y) + b2f(v2.y) + b2f(v3.y)
            + b2f(v4.y) + b2f(v5.y) + b2f(v6.y) + b2f(v7.y);
    }
    for (; j + half < s1; j += 2) {
        ushort2 v = *(const ushort2*)(q2 + (size_t)col[j + half] * 64 + ch);
        ax += b2f(v.x); ay += b2f(v.y);
    }
    ax += __shfl_xor(ax, 32);
    ay += __shfl_xor(ay, 32);
    if (half == 0) {
        float inv = (dn > 0) ? 1.0f / (float)dn : 0.0f;
        float2 pv = *(const float2*)(p2 + (size_t)node * 64 + ch);
        float2 bi = *(const float2*)(bias + ch);
        float2 o;
        o.x = ax * inv + pv.x + bi.x;
        o.y = ay * inv + pv.y + bi.y;
        *(float2*)(out + (size_t)node * 64 + ch) = o;
    }
}

extern "C" void kernel_launch(void* const* d_in, const int* in_sizes, int n_in,
                              void* d_out, int out_size, void* d_ws, size_t ws_size,
                              hipStream_t stream) {
    const float* x   = (const float*)d_in[0];
    const int* ei    = (const int*)d_in[1];
    const float* Wl1 = (const float*)d_in[2];
    const float* bl1 = (const float*)d_in[3];
    const float* Wr1 = (const float*)d_in[4];
    const float* Wl2 = (const float*)d_in[5];
    const float* bl2 = (const float*)d_in[6];
    const float* Wr2 = (const float*)d_in[7];

    const int N = in_sizes[0] / IN_CH;   // 100000
    const int E = in_sizes[1] / 2;       // 1600000
    const int* src = ei;
    const int* dst = ei + E;

    char* p = (char*)d_ws;
    auto carve = [&](size_t bytes) -> void* {
        void* q = (void*)p;
        p += (bytes + 255) & ~(size_t)255;
        return q;
    };
    int* cursor   = (int*)carve(NBUCK * 4);
    int* ebuf     = (int*)carve((size_t)NBUCK * CAP * 4);
    int* col      = (int*)carve((size_t)NBUCK * CAP * 4);
    int* row_ptr  = (int*)carve((size_t)N * 4);
    int* deg      = (int*)carve((size_t)N * 4);
    ushort* q1    = (ushort*)carve((size_t)2 * N * 64 * 2);  // two planes [N][64]
    ushort* p1    = (ushort*)carve((size_t)N * 128 * 2);
    ushort* hb    = (ushort*)carve((size_t)N * 128 * 2);
    ushort* q2    = (ushort*)carve((size_t)N * 64 * 2);
    float* p2     = (float*)carve((size_t)N * 64 * 4);
    (void)ws_size; (void)n_in;

    float* out = (float*)d_out;
    (void)out_size;

    // ---- partition + CSR build ----
    (void)hipMemsetAsync(cursor, 0, NBUCK * 4, stream);
    k_part<<<(E + PART_EPB - 1) / PART_EPB, 256, 0, stream>>>(src, dst, cursor, ebuf, E);
    k_bbuild<<<NBUCK, 512, 0, stream>>>(ebuf, cursor, row_ptr, deg, col, N);

    // ---- layer 1: [Q1|P1] = x @ [Wl1;Wr1].T; h = ReLU(mean(Q1)+P1+b1) ----
    k_wgemm<256, 0><<<(N + 127) / 128, 256, 0, stream>>>(
        x, nullptr, Wl1, Wr1, q1, p1, nullptr, nullptr, N);
    k_agg1<<<(N + 3) / 4, 256, 0, stream>>>(
        row_ptr, deg, col, q1, p1, bl1, hb, N, 0);
    k_agg1<<<(N + 3) / 4, 256, 0, stream>>>(
        row_ptr, deg, col, q1 + (size_t)N * 64, p1, bl1, hb, N, 64);

    // ---- layer 2: [Q2|P2] = hb @ [Wl2;Wr2].T; out = mean(Q2)+P2+b2 ----
    k_wgemm<128, 1><<<(N + 127) / 128, 256, 0, stream>>>(
        nullptr, hb, Wl2, Wr2, nullptr, nullptr, q2, p2, N);
    k_agg2<<<(N + 3) / 4, 256, 0, stream>>>(row_ptr, deg, col, q2, p2, bl2, out, N);
}